// Round 18
// baseline (552.113 us; speedup 1.0000x reference)
//
#include <hip/hip_runtime.h>

#define Bb 4
#define Cc 256
#define Nn 32768

typedef short s16x8 __attribute__((ext_vector_type(8)));
typedef float f32x4 __attribute__((ext_vector_type(4)));
typedef float f32x4v __attribute__((ext_vector_type(4)));

__device__ __forceinline__ unsigned short bfh(float f) {
    union { float f; unsigned u; } c; c.f = f;
    unsigned u = c.u + 0x7fffu + ((c.u >> 16) & 1u);
    return (unsigned short)(u >> 16);
}
__device__ __forceinline__ unsigned fbits(float f) {
    union { float f; unsigned u; } c; c.f = f; return c.u;
}
__device__ __forceinline__ float fof(unsigned u) {
    union { unsigned u; float f; } c; c.u = u; return c.f;
}

// hi = trunc-bf16 (top 16 bits), lo = rtn-bf16 of residual. 8 floats -> 2x uint4.
__device__ __forceinline__ void cvt8(f32x4v A, f32x4v B, uint4& h, uint4& l) {
    unsigned a0 = fbits(A.x), a1 = fbits(A.y), a2 = fbits(A.z), a3 = fbits(A.w);
    unsigned b0 = fbits(B.x), b1 = fbits(B.y), b2 = fbits(B.z), b3 = fbits(B.w);
    h.x = __builtin_amdgcn_perm(a1, a0, 0x07060302u);
    h.y = __builtin_amdgcn_perm(a3, a2, 0x07060302u);
    h.z = __builtin_amdgcn_perm(b1, b0, 0x07060302u);
    h.w = __builtin_amdgcn_perm(b3, b2, 0x07060302u);
    unsigned l0 = fbits(A.x - fof(a0 & 0xffff0000u)) + 0x8000u;
    unsigned l1 = fbits(A.y - fof(a1 & 0xffff0000u)) + 0x8000u;
    unsigned l2 = fbits(A.z - fof(a2 & 0xffff0000u)) + 0x8000u;
    unsigned l3 = fbits(A.w - fof(a3 & 0xffff0000u)) + 0x8000u;
    unsigned m0 = fbits(B.x - fof(b0 & 0xffff0000u)) + 0x8000u;
    unsigned m1 = fbits(B.y - fof(b1 & 0xffff0000u)) + 0x8000u;
    unsigned m2 = fbits(B.z - fof(b2 & 0xffff0000u)) + 0x8000u;
    unsigned m3 = fbits(B.w - fof(b3 & 0xffff0000u)) + 0x8000u;
    l.x = __builtin_amdgcn_perm(l1, l0, 0x07060302u);
    l.y = __builtin_amdgcn_perm(l3, l2, 0x07060302u);
    l.z = __builtin_amdgcn_perm(m1, m0, 0x07060302u);
    l.w = __builtin_amdgcn_perm(m3, m2, 0x07060302u);
}
__device__ __forceinline__ float s4(f32x4v v) { return (v.x + v.y) + (v.z + v.w); }

// ---------------- Gram via bf16x3 MFMA: BARRIER-FREE, LDS-FREE ---------------
// Every LDS-staged schedule (6 variants, rounds 2-17) pinned at ~105-140us:
// 1 barrier/step lockstep serializes delivery+LDS+cvt+MFMA (~7900cyc/step).
// New: k_out's pattern — per-wave direct global->reg fragments (row=lane&15,
// k=(lane>>4)*8, same mapping as LDS version), cvt8 in-register, depth-2 reg
// sets, zero barriers. Waves self-overlap phases; L2 absorbs the 2x in-block
// operand duplication (quadrant siblings are XCD-chunked onto the same L2).
// Block = 256 thr, 2x2 waves, 128x128 tile per (b,ks,quad); grid 512.
__global__ __launch_bounds__(256, 2) void k_gram(const float* __restrict__ x,
                                                 const float* __restrict__ y,
                                                 float* __restrict__ part,
                                                 float* __restrict__ sxp,
                                                 float* __restrict__ syp,
                                                 int nsplit) {
    int G = Bb * nsplit * 4;                    // 512 when split=32
    int chunk = G >> 3;                         // 64: quads of a (b,ks) same XCD
    int lid = blockIdx.x;
    int bid = (lid & 7) * chunk + (lid >> 3);   // bijective XCD chunk swizzle

    int quad = bid & 3;
    int ti = quad >> 1, tj = quad & 1;
    int ks = (bid >> 2) % nsplit;
    int b  = bid / (4 * nsplit);
    int Kblk = Nn / nsplit;                     // 1024
    int nstep = Kblk >> 5;                      // 32 (even)

    int tid = threadIdx.x;
    int lane = tid & 63;
    int wave = tid >> 6;
    int wwr = wave >> 1, wwc = wave & 1;        // 2x2 wave grid, 64x64 each
    int l15 = lane & 15, lh = lane >> 4;

    const float* Xb = x + (size_t)b * Cc * Nn + (size_t)ks * Kblk + lh * 8;
    const float* Yb = y + (size_t)b * Cc * Nn + (size_t)ks * Kblk + lh * 8;
    const float* ap[4];
    const float* bp[4];
    #pragma unroll
    for (int i = 0; i < 4; ++i) {
        ap[i] = Xb + (size_t)(ti * 128 + wwr * 64 + i * 16 + l15) * Nn;
        bp[i] = Yb + (size_t)(tj * 128 + wwc * 64 + i * 16 + l15) * Nn;
    }

    f32x4 acc[4][4];
    #pragma unroll
    for (int i = 0; i < 4; ++i)
        #pragma unroll
        for (int j = 0; j < 4; ++j)
            #pragma unroll
            for (int z = 0; z < 4; ++z) acc[i][j][z] = 0.f;

    float xs[4] = {0.f, 0.f, 0.f, 0.f};
    float ys[4] = {0.f, 0.f, 0.f, 0.f};

    f32x4v A0[8], B0[8], A1[8], B1[8];

    #define GLD(AS, BS, kb) do { \
        _Pragma("unroll") \
        for (int i = 0; i < 4; ++i) { \
            AS[2 * i]     = ((const f32x4v*)(ap[i] + (kb)))[0]; \
            AS[2 * i + 1] = ((const f32x4v*)(ap[i] + (kb)))[1]; \
            BS[2 * i]     = ((const f32x4v*)(bp[i] + (kb)))[0]; \
            BS[2 * i + 1] = ((const f32x4v*)(bp[i] + (kb)))[1]; \
        } } while (0)

    #define GSTEP(AS, BS, nkb, donext) do { \
        s16x8 Ah[4], Al[4], Bh[4], Bl[4]; \
        _Pragma("unroll") \
        for (int i = 0; i < 4; ++i) { \
            uint4 h, q; \
            cvt8(AS[2 * i], AS[2 * i + 1], h, q); \
            Ah[i] = __builtin_bit_cast(s16x8, h); \
            Al[i] = __builtin_bit_cast(s16x8, q); \
            if (wwc == 0) xs[i] += s4(AS[2 * i]) + s4(AS[2 * i + 1]); \
            cvt8(BS[2 * i], BS[2 * i + 1], h, q); \
            Bh[i] = __builtin_bit_cast(s16x8, h); \
            Bl[i] = __builtin_bit_cast(s16x8, q); \
            if (wwr == 0) ys[i] += s4(BS[2 * i]) + s4(BS[2 * i + 1]); \
        } \
        if (donext) GLD(AS, BS, nkb); \
        _Pragma("unroll") \
        for (int j = 0; j < 4; ++j) \
            _Pragma("unroll") \
            for (int i = 0; i < 4; ++i) { \
                acc[i][j] = __builtin_amdgcn_mfma_f32_16x16x32_bf16(Ah[i], Bh[j], acc[i][j], 0, 0, 0); \
                acc[i][j] = __builtin_amdgcn_mfma_f32_16x16x32_bf16(Ah[i], Bl[j], acc[i][j], 0, 0, 0); \
                acc[i][j] = __builtin_amdgcn_mfma_f32_16x16x32_bf16(Al[i], Bh[j], acc[i][j], 0, 0, 0); \
            } \
        } while (0)

    GLD(A0, B0, 0);
    GLD(A1, B1, 32);
    for (int t = 0; t < nstep; t += 2) {
        GSTEP(A0, B0, (t + 2) * 32, t + 2 < nstep);
        GSTEP(A1, B1, (t + 3) * 32, t + 3 < nstep);
    }
    #undef GSTEP
    #undef GLD

    // row sums: lanes l15, l15+16, l15+32, l15+48 hold k-group partials of the
    // same row -> xor-reduce over lh; counted once chip-wide via (tj,wwc)/(ti,wwr)
    #pragma unroll
    for (int i = 0; i < 4; ++i) {
        xs[i] += __shfl_xor(xs[i], 16);
        xs[i] += __shfl_xor(xs[i], 32);
        ys[i] += __shfl_xor(ys[i], 16);
        ys[i] += __shfl_xor(ys[i], 32);
    }
    size_t sbase = ((size_t)b * nsplit + ks) * 256;
    if (tj == 0 && wwc == 0 && lh == 0) {
        #pragma unroll
        for (int i = 0; i < 4; ++i)
            sxp[sbase + ti * 128 + wwr * 64 + i * 16 + l15] = xs[i];
    }
    if (ti == 0 && wwr == 0 && lh == 0) {
        #pragma unroll
        for (int i = 0; i < 4; ++i)
            syp[sbase + tj * 128 + wwc * 64 + i * 16 + l15] = ys[i];
    }

    // write partials (C/D: col = lane&15, row = (lane>>4)*4 + reg)
    float* P = part + ((size_t)b * nsplit + ks) * Cc * Cc;
    #pragma unroll
    for (int i = 0; i < 4; ++i)
        #pragma unroll
        for (int j = 0; j < 4; ++j)
            #pragma unroll
            for (int reg = 0; reg < 4; ++reg) {
                int gi = ti * 128 + wwr * 64 + i * 16 + (lane >> 4) * 4 + reg;
                int gj = tj * 128 + wwc * 64 + j * 16 + (lane & 15);
                P[(size_t)gi * Cc + gj] = acc[i][j][reg];
            }
}

// reduce S partials (float4); blocks >=256 reduce row-sum partials into sx/sy
__global__ __launch_bounds__(256) void k_reduceS(const float* __restrict__ part,
                                                 const float* __restrict__ sxp,
                                                 const float* __restrict__ syp,
                                                 float* __restrict__ S,
                                                 float* __restrict__ sx,
                                                 float* __restrict__ sy, int split) {
    if (blockIdx.x < 256) {
        int t = blockIdx.x * 256 + threadIdx.x;   // 0..65535 float4 units
        int b = t >> 14;
        int rc = t & 16383;
        f32x4v s = {0.f, 0.f, 0.f, 0.f};
        for (int ks = 0; ks < split; ++ks) {
            f32x4v v = ((const f32x4v*)(part + (((size_t)b * split + ks) << 16)))[rc];
            s += v;
        }
        ((f32x4v*)S)[t] = s;
    } else {
        int flat = (blockIdx.x - 256) * 256 + threadIdx.x;  // 0..2047
        int b = flat >> 9, rem = flat & 511, which = rem >> 8, c = rem & 255;
        const float* src = (which ? syp : sxp) + (size_t)b * split * 256 + c;
        float s = 0.f;
        for (int ks = 0; ks < split; ++ks) s += src[(size_t)ks * 256];
        (which ? sy : sx)[b * 256 + c] = s;
    }
}

// ---------------- fused scores+softmax+M: 8 rows per block -------------------
__global__ __launch_bounds__(256) void k_attn(const float* __restrict__ S,
                                              const float* __restrict__ sx,
                                              const float* __restrict__ sy,
                                              const float* __restrict__ Wq,
                                              const float* __restrict__ Wk,
                                              const float* __restrict__ Wv,
                                              const float* __restrict__ bq,
                                              const float* __restrict__ bk,
                                              const float* __restrict__ bv,
                                              short* __restrict__ Mbf,
                                              float* __restrict__ cb) {
    __shared__ float wq_lds[8][256];
    __shared__ float u_lds[8][256];
    __shared__ float p_lds[8][256];
    __shared__ float wv_lds[32][256];
    __shared__ float sx_lds[256], sy_lds[256];
    __shared__ float qx_lds[8];

    int b = blockIdx.x >> 5;
    int i0 = (blockIdx.x & 31) << 3;
    int tid = threadIdx.x;
    int lane = tid & 63, wv4 = tid >> 6;

    float bqv[8];
    #pragma unroll
    for (int ii = 0; ii < 8; ++ii) {
        wq_lds[ii][tid] = Wq[(size_t)(i0 + ii) * Cc + tid];
        bqv[ii] = bq[i0 + ii];
    }
    sx_lds[tid] = sx[b * Cc + tid];
    sy_lds[tid] = sy[b * Cc + tid];
    __syncthreads();

    float u[8] = {};
    const float* Sb = S + (size_t)b * Cc * Cc + tid;
    #pragma unroll 4
    for (int c = 0; c < Cc; ++c) {
        float s = Sb[(size_t)c * Cc];
        #pragma unroll
        for (int ii = 0; ii < 8; ++ii) u[ii] += wq_lds[ii][c] * s;
    }
    #pragma unroll
    for (int ii = 0; ii < 8; ++ii) u_lds[ii][tid] = u[ii] + bqv[ii] * sy_lds[tid];

    #pragma unroll
    for (int rr = 0; rr < 2; ++rr) {
        int ii = wv4 * 2 + rr;
        float p = 0.f;
        #pragma unroll
        for (int k = 0; k < 4; ++k) { int c = lane + 64 * k; p += wq_lds[ii][c] * sx_lds[c]; }
        #pragma unroll
        for (int m = 1; m < 64; m <<= 1) p += __shfl_xor(p, m);
        if (lane == 0) qx_lds[ii] = p;
    }
    __syncthreads();

    float sc[8] = {};
    const float* WkRow = Wk + (size_t)tid * Cc;
    for (int ch = 0; ch < 8; ++ch) {
        float wkr[32];
        #pragma unroll
        for (int k = 0; k < 8; ++k)
            *(float4*)&wkr[4 * k] = ((const float4*)(WkRow + ch * 32))[k];
        #pragma unroll
        for (int dd = 0; dd < 32; ++dd) {
            float w = wkr[dd];
            #pragma unroll
            for (int ii = 0; ii < 8; ++ii) sc[ii] += u_lds[ii][ch * 32 + dd] * w;
        }
    }
    float bkj = bk[tid];
    #pragma unroll
    for (int ii = 0; ii < 8; ++ii) {
        sc[ii] += (qx_lds[ii] + 32768.0f * bqv[ii]) * bkj;
        p_lds[ii][tid] = sc[ii];
    }
    __syncthreads();

    #pragma unroll
    for (int rr = 0; rr < 2; ++rr) {
        int ii = wv4 * 2 + rr;
        float v0 = p_lds[ii][lane], v1 = p_lds[ii][lane + 64];
        float v2 = p_lds[ii][lane + 128], v3 = p_lds[ii][lane + 192];
        float mx = fmaxf(fmaxf(v0, v1), fmaxf(v2, v3));
        #pragma unroll
        for (int m = 1; m < 64; m <<= 1) mx = fmaxf(mx, __shfl_xor(mx, m));
        float e0 = expf(v0 - mx), e1 = expf(v1 - mx), e2 = expf(v2 - mx), e3 = expf(v3 - mx);
        float ssum = (e0 + e1) + (e2 + e3);
        #pragma unroll
        for (int m = 1; m < 64; m <<= 1) ssum += __shfl_xor(ssum, m);
        float inv = 1.0f / ssum;
        float w0 = e0 * inv, w1 = e1 * inv, w2 = e2 * inv, w3 = e3 * inv;
        p_lds[ii][lane] = w0; p_lds[ii][lane + 64] = w1;
        p_lds[ii][lane + 128] = w2; p_lds[ii][lane + 192] = w3;
        float cbp = w0 * bv[lane] + w1 * bv[lane + 64] + w2 * bv[lane + 128] + w3 * bv[lane + 192];
        #pragma unroll
        for (int m = 1; m < 64; m <<= 1) cbp += __shfl_xor(cbp, m);
        if (lane == 0) cb[b * Cc + i0 + ii] = cbp;
    }
    __syncthreads();

    float m[8] = {};
    for (int jc = 0; jc < 8; ++jc) {
        #pragma unroll
        for (int k = 0; k < 8; ++k) {
            int fidx = k * 256 + tid;
            int jj = fidx >> 6, f4 = fidx & 63;
            *(float4*)&wv_lds[jj][4 * f4] =
                *(const float4*)(Wv + (size_t)(jc * 32 + jj) * Cc + 4 * f4);
        }
        __syncthreads();
        #pragma unroll 4
        for (int jj = 0; jj < 32; ++jj) {
            float w = wv_lds[jj][tid];
            #pragma unroll
            for (int ii = 0; ii < 8; ++ii) m[ii] += p_lds[ii][jc * 32 + jj] * w;
        }
        __syncthreads();
    }
    #pragma unroll
    for (int ii = 0; ii < 8; ++ii)
        Mbf[((size_t)(b * Cc + i0 + ii)) * Cc + tid] = (short)bfh(m[ii]);
}

// out[b,i,n] = sum_c M[b,i,c]*y[b,c,n] + cb[b,i]
// 512 thr / 8 waves; issue order af(s+1) -> y(s+2) -> MFMA(af(s)).
__global__ __launch_bounds__(512, 2) void k_out_mfma(const short* __restrict__ Mbf,
                                                     const float* __restrict__ y,
                                                     const float* __restrict__ cb,
                                                     float* __restrict__ out) {
    int tid = threadIdx.x;
    int lane = tid & 63;
    int wave = tid >> 6;
    int wr = wave >> 2, wc = wave & 3;
    int bid = blockIdx.x;           // 0..1023
    int b = bid >> 8, grp = bid & 255;
    int nbase = grp * 128 + wc * 32;
    const float* Y = y + (size_t)b * Cc * Nn;
    const short* M = Mbf + (size_t)b * Cc * Cc;
    int l15 = lane & 15;
    int cbase = 8 * (lane >> 4);
    int n0 = nbase + l15;

    f32x4 acc[8][2];
    #pragma unroll
    for (int ti = 0; ti < 8; ++ti)
        #pragma unroll
        for (int nb = 0; nb < 2; ++nb)
            #pragma unroll
            for (int z = 0; z < 4; ++z) acc[ti][nb][z] = 0.f;

    s16x8 af0[8], af1[8];
    float ya0[8], yb0[8], ya1[8], yb1[8];

    #define AFLD(AF, s) do { int c0 = 32 * (s) + cbase; \
        _Pragma("unroll") \
        for (int ti = 0; ti < 8; ++ti) \
            AF[ti] = *(const s16x8*)&M[(size_t)(wr * 128 + ti * 16 + l15) * Cc + c0]; \
        } while (0)

    #define LDY(YA, YB, s) do { int c0 = 32 * (s) + cbase; \
        _Pragma("unroll") \
        for (int j = 0; j < 8; ++j) { \
            YA[j] = Y[(size_t)(c0 + j) * Nn + n0]; \
            YB[j] = Y[(size_t)(c0 + j) * Nn + n0 + 16]; \
        } } while (0)

    #define OSTEP(AF, AFN, YA, YB, s) do { \
        s16x8 bf0, bf1; \
        _Pragma("unroll") \
        for (int j = 0; j < 8; ++j) { bf0[j] = (short)bfh(YA[j]); bf1[j] = (short)bfh(YB[j]); } \
        if ((s) + 1 < 8) AFLD(AFN, (s) + 1); \
        if ((s) + 2 < 8) LDY(YA, YB, (s) + 2); \
        _Pragma("unroll") \
        for (int ti = 0; ti < 8; ++ti) { \
            acc[ti][0] = __builtin_amdgcn_mfma_f32_16x16x32_bf16(AF[ti], bf0, acc[ti][0], 0, 0, 0); \
            acc[ti][1] = __builtin_amdgcn_mfma_f32_16x16x32_bf16(AF[ti], bf1, acc[ti][1], 0, 0, 0); \
        } } while (0)

    AFLD(af0, 0);
    LDY(ya0, yb0, 0);
    LDY(ya1, yb1, 1);
    for (int s = 0; s < 8; s += 2) {
        OSTEP(af0, af1, ya0, yb0, s);
        OSTEP(af1, af0, ya1, yb1, s + 1);
    }
    #undef OSTEP
    #undef LDY
    #undef AFLD

    #pragma unroll
    for (int ti = 0; ti < 8; ++ti)
        #pragma unroll
        for (int nb = 0; nb < 2; ++nb)
            #pragma unroll
            for (int reg = 0; reg < 4; ++reg) {
                int i = wr * 128 + ti * 16 + (lane >> 4) * 4 + reg;
                out[((size_t)b * Cc + i) * Nn + nbase + nb * 16 + l15] =
                    acc[ti][nb][reg] + cb[b * Cc + i];
            }
}

extern "C" void kernel_launch(void* const* d_in, const int* in_sizes, int n_in,
                              void* d_out, int out_size, void* d_ws, size_t ws_size,
                              hipStream_t stream) {
    const float* x  = (const float*)d_in[0];
    const float* y  = (const float*)d_in[1];
    const float* Wq = (const float*)d_in[2];
    const float* bq = (const float*)d_in[3];
    const float* Wk = (const float*)d_in[4];
    const float* bk = (const float*)d_in[5];
    const float* Wv = (const float*)d_in[6];
    const float* bv = (const float*)d_in[7];
    float* out = (float*)d_out;

    float* ws = (float*)d_ws;
    size_t off = 0;
    float* S  = ws + off; off += (size_t)Bb * Cc * Cc;
    float* sx = ws + off; off += Bb * Cc;
    float* sy = ws + off; off += Bb * Cc;
    short* Mbf = (short*)(ws + off); off += (size_t)Bb * Cc * Cc / 2;
    float* cb = ws + off; off += Bb * Cc;
    float* sxp = ws + off; off += (size_t)Bb * 64 * 256;
    float* syp = ws + off; off += (size_t)Bb * 64 * 256;
    float* part = ws + off;

    size_t avail = ws_size / 4 - off;
    int split = 32;
    while (split > 16 && (size_t)split * Bb * Cc * Cc > avail) split >>= 1;

    k_gram<<<Bb * split * 4, 256, 0, stream>>>(x, y, part, sxp, syp, split);
    k_reduceS<<<264, 256, 0, stream>>>(part, sxp, syp, S, sx, sy, split);
    k_attn<<<Bb * 32, 256, 0, stream>>>(S, sx, sy, Wq, Wk, Wv, bq, bk, bv, Mbf, cb);
    k_out_mfma<<<1024, 512, 0, stream>>>(Mbf, y, cb, out);
}

// Round 19
// 220.350 us; speedup vs baseline: 2.5056x; 2.5056x over previous
//
#include <hip/hip_runtime.h>

#define Bb 4
#define Cc 256
#define Nn 32768

typedef short s16x8 __attribute__((ext_vector_type(8)));
typedef float f32x4 __attribute__((ext_vector_type(4)));
typedef float f32x4v __attribute__((ext_vector_type(4)));

__device__ __forceinline__ unsigned short bfh(float f) {
    union { float f; unsigned u; } c; c.f = f;
    unsigned u = c.u + 0x7fffu + ((c.u >> 16) & 1u);
    return (unsigned short)(u >> 16);
}
__device__ __forceinline__ unsigned fbits(float f) {
    union { float f; unsigned u; } c; c.f = f; return c.u;
}
__device__ __forceinline__ float fof(unsigned u) {
    union { unsigned u; float f; } c; c.u = u; return c.f;
}
__device__ __forceinline__ int swz(int l) { return l ^ ((l >> 3) & 6); }

// hi = trunc-bf16 (top 16 bits), lo = rtn-bf16 of residual. 8 floats -> 2x uint4.
__device__ __forceinline__ void cvt8(f32x4v A, f32x4v B, uint4& h, uint4& l) {
    unsigned a0 = fbits(A.x), a1 = fbits(A.y), a2 = fbits(A.z), a3 = fbits(A.w);
    unsigned b0 = fbits(B.x), b1 = fbits(B.y), b2 = fbits(B.z), b3 = fbits(B.w);
    h.x = __builtin_amdgcn_perm(a1, a0, 0x07060302u);
    h.y = __builtin_amdgcn_perm(a3, a2, 0x07060302u);
    h.z = __builtin_amdgcn_perm(b1, b0, 0x07060302u);
    h.w = __builtin_amdgcn_perm(b3, b2, 0x07060302u);
    unsigned l0 = fbits(A.x - fof(a0 & 0xffff0000u)) + 0x8000u;
    unsigned l1 = fbits(A.y - fof(a1 & 0xffff0000u)) + 0x8000u;
    unsigned l2 = fbits(A.z - fof(a2 & 0xffff0000u)) + 0x8000u;
    unsigned l3 = fbits(A.w - fof(a3 & 0xffff0000u)) + 0x8000u;
    unsigned m0 = fbits(B.x - fof(b0 & 0xffff0000u)) + 0x8000u;
    unsigned m1 = fbits(B.y - fof(b1 & 0xffff0000u)) + 0x8000u;
    unsigned m2 = fbits(B.z - fof(b2 & 0xffff0000u)) + 0x8000u;
    unsigned m3 = fbits(B.w - fof(b3 & 0xffff0000u)) + 0x8000u;
    l.x = __builtin_amdgcn_perm(l1, l0, 0x07060302u);
    l.y = __builtin_amdgcn_perm(l3, l2, 0x07060302u);
    l.z = __builtin_amdgcn_perm(m1, m0, 0x07060302u);
    l.w = __builtin_amdgcn_perm(m3, m2, 0x07060302u);
}
__device__ __forceinline__ float s4(f32x4v v) { return (v.x + v.y) + (v.z + v.w); }

// ---------------- Gram via bf16x3 MFMA, 1-barrier/step LDS double-buffer -----
// x loads NONTEMPORAL (x read exactly once pipeline-wide): keeps y cached for
// sibling blocks and k_out. Measured best: gram ~104-107us (rounds 15/16/17).
__global__ __launch_bounds__(512, 2) void k_gram(const float* __restrict__ x,
                                                 const float* __restrict__ y,
                                                 float* __restrict__ part,
                                                 float* __restrict__ sxp,
                                                 float* __restrict__ syp,
                                                 int nsplit) {
    extern __shared__ short smem[];             // 2 x 24576 shorts

    int G = Bb * nsplit * 2;                    // 256 when split=32
    int chunk = G >> 3;
    int lid = blockIdx.x;
    int bid = (lid & 7) * chunk + (lid >> 3);   // bijective: sibling halves same XCD

    int half = bid & 1;
    int ks = (bid >> 1) % nsplit;
    int b = bid / (2 * nsplit);
    int Kblk = Nn / nsplit;
    int nstep = Kblk >> 5;                      // 32 for split=32 (even)

    const float* X = x + (size_t)b * Cc * Nn + (size_t)(half * 128) * Nn + (size_t)ks * Kblk;
    const float* Y = y + (size_t)b * Cc * Nn + (size_t)ks * Kblk;

    int tid = threadIdx.x;
    int lane = tid & 63;
    int wave = tid >> 6;
    int wr = wave >> 2, wc = wave & 3;          // 2x4 wave grid, 64x64 each

    int xr = tid >> 2, xq = tid & 3;            // X: row, 8-col chunk
    const float* px = X + (size_t)xr * Nn + xq * 8;
    int xl = (xr & 15) + 16 * xq;
    int xo = ((xr >> 4) * 64 + swz(xl)) * 8;    // into XH region (offset 0)
    int yr = tid >> 1, yh2 = tid & 1;           // Y: row, 16-col half
    const float* py = Y + (size_t)yr * Nn + yh2 * 16;
    int yl0 = (yr & 15) + 32 * yh2, yl1 = yl0 + 16;
    int yo0 = ((yr >> 4) * 64 + swz(yl0)) * 8;  // into YH region (offset 8192)
    int yo1 = ((yr >> 4) * 64 + swz(yl1)) * 8;

    f32x4 acc[4][4];
    #pragma unroll
    for (int i = 0; i < 4; ++i)
        #pragma unroll
        for (int j = 0; j < 4; ++j)
            #pragma unroll
            for (int z = 0; z < 4; ++z) acc[i][j][z] = 0.f;

    float xsum = 0.f, ysum = 0.f;
    f32x4v A0[2], B0[4], A1[2], B1[4];

    #define LDX(A, B, kb) do { \
        A[0] = __builtin_nontemporal_load((const f32x4v*)(px + (kb)) + 0); \
        A[1] = __builtin_nontemporal_load((const f32x4v*)(px + (kb)) + 1); \
        B[0] = ((const f32x4v*)(py + (kb)))[0]; B[1] = ((const f32x4v*)(py + (kb)))[1]; \
        B[2] = ((const f32x4v*)(py + (kb)))[2]; B[3] = ((const f32x4v*)(py + (kb)))[3]; \
    } while (0)

    #define COMPUTE(Sb) do { \
        int sl = swz(lane); \
        s16x8 ah[4], al[4]; \
        _Pragma("unroll") \
        for (int i = 0; i < 4; ++i) { \
            int fr = (wr * 4 + i) * 64 + sl; \
            ah[i] = *(const s16x8*)&(Sb)[fr * 8]; \
            al[i] = *(const s16x8*)&(Sb)[4096 + fr * 8]; \
        } \
        _Pragma("unroll") \
        for (int j = 0; j < 4; ++j) { \
            int fr = (wc * 4 + j) * 64 + sl; \
            s16x8 bh = *(const s16x8*)&(Sb)[8192 + fr * 8]; \
            s16x8 bl = *(const s16x8*)&(Sb)[16384 + fr * 8]; \
            _Pragma("unroll") \
            for (int i = 0; i < 4; ++i) { \
                acc[i][j] = __builtin_amdgcn_mfma_f32_16x16x32_bf16(ah[i], bh, acc[i][j], 0, 0, 0); \
                acc[i][j] = __builtin_amdgcn_mfma_f32_16x16x32_bf16(ah[i], bl, acc[i][j], 0, 0, 0); \
                acc[i][j] = __builtin_amdgcn_mfma_f32_16x16x32_bf16(al[i], bh, acc[i][j], 0, 0, 0); \
            } \
        } \
    } while (0)

    // one raw barrier per step: lgkm-only wait (ds_writes visible), no vmcnt drain
    #define GSTEP(A, B, nkb, donext, cur) do { \
        uint4 hx, qxv, hy0, qy0, hy1, qy1; \
        cvt8(A[0], A[1], hx, qxv); \
        cvt8(B[0], B[1], hy0, qy0); \
        cvt8(B[2], B[3], hy1, qy1); \
        xsum += s4(A[0]) + s4(A[1]); \
        if (half == 0) ysum += s4(B[0]) + s4(B[1]) + s4(B[2]) + s4(B[3]); \
        short* Sb = smem + (cur); \
        *(uint4*)&Sb[xo] = hx;  *(uint4*)&Sb[4096 + xo] = qxv; \
        *(uint4*)&Sb[8192 + yo0] = hy0; *(uint4*)&Sb[16384 + yo0] = qy0; \
        *(uint4*)&Sb[8192 + yo1] = hy1; *(uint4*)&Sb[16384 + yo1] = qy1; \
        if (donext) LDX(A, B, nkb); \
        asm volatile("s_waitcnt lgkmcnt(0)" ::: "memory"); \
        __builtin_amdgcn_sched_barrier(0); \
        __builtin_amdgcn_s_barrier(); \
        __builtin_amdgcn_sched_barrier(0); \
        COMPUTE(Sb); \
    } while (0)

    LDX(A0, B0, 0);
    LDX(A1, B1, 32);
    for (int t = 0; t < nstep; t += 2) {
        GSTEP(A0, B0, (t + 2) * 32, t + 2 < nstep, 0);
        GSTEP(A1, B1, (t + 3) * 32, t + 3 < nstep, 24576);
    }
    #undef GSTEP
    #undef COMPUTE
    #undef LDX

    // row-sum partials: X shared by 4 threads (xq), Y by 2 (yh2)
    xsum += __shfl_xor(xsum, 1);
    xsum += __shfl_xor(xsum, 2);
    ysum += __shfl_xor(ysum, 1);
    if (xq == 0) sxp[((size_t)b * nsplit + ks) * 256 + half * 128 + xr] = xsum;
    if (half == 0 && yh2 == 0) syp[((size_t)b * nsplit + ks) * 256 + yr] = ysum;

    // write partials (C/D: col = lane&15, row = (lane>>4)*4 + reg)
    float* P = part + ((size_t)b * nsplit + ks) * Cc * Cc;
    #pragma unroll
    for (int i = 0; i < 4; ++i)
        #pragma unroll
        for (int j = 0; j < 4; ++j)
            #pragma unroll
            for (int reg = 0; reg < 4; ++reg) {
                int gi = half * 128 + wr * 64 + i * 16 + (lane >> 4) * 4 + reg;
                int gj = wc * 64 + j * 16 + (lane & 15);
                P[(size_t)gi * Cc + gj] = acc[i][j][reg];
            }
}

// reduce S partials (float4, nontemporal reads: partials are consumed once);
// blocks >=256 reduce row-sum partials into sx/sy
__global__ __launch_bounds__(256) void k_reduceS(const float* __restrict__ part,
                                                 const float* __restrict__ sxp,
                                                 const float* __restrict__ syp,
                                                 float* __restrict__ S,
                                                 float* __restrict__ sx,
                                                 float* __restrict__ sy, int split) {
    if (blockIdx.x < 256) {
        int t = blockIdx.x * 256 + threadIdx.x;   // 0..65535 float4 units
        int b = t >> 14;
        int rc = t & 16383;
        f32x4v s = {0.f, 0.f, 0.f, 0.f};
        for (int ks = 0; ks < split; ++ks) {
            f32x4v v = __builtin_nontemporal_load(
                (const f32x4v*)(part + (((size_t)b * split + ks) << 16)) + rc);
            s += v;
        }
        ((f32x4v*)S)[t] = s;
    } else {
        int flat = (blockIdx.x - 256) * 256 + threadIdx.x;  // 0..2047
        int b = flat >> 9, rem = flat & 511, which = rem >> 8, c = rem & 255;
        const float* src = (which ? syp : sxp) + (size_t)b * split * 256 + c;
        float s = 0.f;
        for (int ks = 0; ks < split; ++ks)
            s += __builtin_nontemporal_load(src + (size_t)ks * 256);
        (which ? sy : sx)[b * 256 + c] = s;
    }
}

// ---------------- fused scores+softmax+M: 8 rows per block -------------------
__global__ __launch_bounds__(256) void k_attn(const float* __restrict__ S,
                                              const float* __restrict__ sx,
                                              const float* __restrict__ sy,
                                              const float* __restrict__ Wq,
                                              const float* __restrict__ Wk,
                                              const float* __restrict__ Wv,
                                              const float* __restrict__ bq,
                                              const float* __restrict__ bk,
                                              const float* __restrict__ bv,
                                              short* __restrict__ Mbf,
                                              float* __restrict__ cb) {
    __shared__ float wq_lds[8][256];
    __shared__ float u_lds[8][256];
    __shared__ float p_lds[8][256];
    __shared__ float wv_lds[32][256];
    __shared__ float sx_lds[256], sy_lds[256];
    __shared__ float qx_lds[8];

    int b = blockIdx.x >> 5;
    int i0 = (blockIdx.x & 31) << 3;
    int tid = threadIdx.x;
    int lane = tid & 63, wv4 = tid >> 6;

    float bqv[8];
    #pragma unroll
    for (int ii = 0; ii < 8; ++ii) {
        wq_lds[ii][tid] = Wq[(size_t)(i0 + ii) * Cc + tid];
        bqv[ii] = bq[i0 + ii];
    }
    sx_lds[tid] = sx[b * Cc + tid];
    sy_lds[tid] = sy[b * Cc + tid];
    __syncthreads();

    float u[8] = {};
    const float* Sb = S + (size_t)b * Cc * Cc + tid;
    #pragma unroll 4
    for (int c = 0; c < Cc; ++c) {
        float s = Sb[(size_t)c * Cc];
        #pragma unroll
        for (int ii = 0; ii < 8; ++ii) u[ii] += wq_lds[ii][c] * s;
    }
    #pragma unroll
    for (int ii = 0; ii < 8; ++ii) u_lds[ii][tid] = u[ii] + bqv[ii] * sy_lds[tid];

    #pragma unroll
    for (int rr = 0; rr < 2; ++rr) {
        int ii = wv4 * 2 + rr;
        float p = 0.f;
        #pragma unroll
        for (int k = 0; k < 4; ++k) { int c = lane + 64 * k; p += wq_lds[ii][c] * sx_lds[c]; }
        #pragma unroll
        for (int m = 1; m < 64; m <<= 1) p += __shfl_xor(p, m);
        if (lane == 0) qx_lds[ii] = p;
    }
    __syncthreads();

    float sc[8] = {};
    const float* WkRow = Wk + (size_t)tid * Cc;
    for (int ch = 0; ch < 8; ++ch) {
        float wkr[32];
        #pragma unroll
        for (int k = 0; k < 8; ++k)
            *(float4*)&wkr[4 * k] = ((const float4*)(WkRow + ch * 32))[k];
        #pragma unroll
        for (int dd = 0; dd < 32; ++dd) {
            float w = wkr[dd];
            #pragma unroll
            for (int ii = 0; ii < 8; ++ii) sc[ii] += u_lds[ii][ch * 32 + dd] * w;
        }
    }
    float bkj = bk[tid];
    #pragma unroll
    for (int ii = 0; ii < 8; ++ii) {
        sc[ii] += (qx_lds[ii] + 32768.0f * bqv[ii]) * bkj;
        p_lds[ii][tid] = sc[ii];
    }
    __syncthreads();

    #pragma unroll
    for (int rr = 0; rr < 2; ++rr) {
        int ii = wv4 * 2 + rr;
        float v0 = p_lds[ii][lane], v1 = p_lds[ii][lane + 64];
        float v2 = p_lds[ii][lane + 128], v3 = p_lds[ii][lane + 192];
        float mx = fmaxf(fmaxf(v0, v1), fmaxf(v2, v3));
        #pragma unroll
        for (int m = 1; m < 64; m <<= 1) mx = fmaxf(mx, __shfl_xor(mx, m));
        float e0 = expf(v0 - mx), e1 = expf(v1 - mx), e2 = expf(v2 - mx), e3 = expf(v3 - mx);
        float ssum = (e0 + e1) + (e2 + e3);
        #pragma unroll
        for (int m = 1; m < 64; m <<= 1) ssum += __shfl_xor(ssum, m);
        float inv = 1.0f / ssum;
        float w0 = e0 * inv, w1 = e1 * inv, w2 = e2 * inv, w3 = e3 * inv;
        p_lds[ii][lane] = w0; p_lds[ii][lane + 64] = w1;
        p_lds[ii][lane + 128] = w2; p_lds[ii][lane + 192] = w3;
        float cbp = w0 * bv[lane] + w1 * bv[lane + 64] + w2 * bv[lane + 128] + w3 * bv[lane + 192];
        #pragma unroll
        for (int m = 1; m < 64; m <<= 1) cbp += __shfl_xor(cbp, m);
        if (lane == 0) cb[b * Cc + i0 + ii] = cbp;
    }
    __syncthreads();

    float m[8] = {};
    for (int jc = 0; jc < 8; ++jc) {
        #pragma unroll
        for (int k = 0; k < 8; ++k) {
            int fidx = k * 256 + tid;
            int jj = fidx >> 6, f4 = fidx & 63;
            *(float4*)&wv_lds[jj][4 * f4] =
                *(const float4*)(Wv + (size_t)(jc * 32 + jj) * Cc + 4 * f4);
        }
        __syncthreads();
        #pragma unroll 4
        for (int jj = 0; jj < 32; ++jj) {
            float w = wv_lds[jj][tid];
            #pragma unroll
            for (int ii = 0; ii < 8; ++ii) m[ii] += p_lds[ii][jc * 32 + jj] * w;
        }
        __syncthreads();
    }
    #pragma unroll
    for (int ii = 0; ii < 8; ++ii)
        Mbf[((size_t)(b * Cc + i0 + ii)) * Cc + tid] = (short)bfh(m[ii]);
}

// out[b,i,n] = sum_c M[b,i,c]*y[b,c,n] + cb[b,i]
// 512 thr / 8 waves; issue order af(s+1) -> y(s+2) -> MFMA(af(s)).
// Normal cached stores (L2 write-allocate assembles full lines).
__global__ __launch_bounds__(512, 2) void k_out_mfma(const short* __restrict__ Mbf,
                                                     const float* __restrict__ y,
                                                     const float* __restrict__ cb,
                                                     float* __restrict__ out) {
    int tid = threadIdx.x;
    int lane = tid & 63;
    int wave = tid >> 6;
    int wr = wave >> 2, wc = wave & 3;
    int bid = blockIdx.x;           // 0..1023
    int b = bid >> 8, grp = bid & 255;
    int nbase = grp * 128 + wc * 32;
    const float* Y = y + (size_t)b * Cc * Nn;
    const short* M = Mbf + (size_t)b * Cc * Cc;
    int l15 = lane & 15;
    int cbase = 8 * (lane >> 4);
    int n0 = nbase + l15;

    f32x4 acc[8][2];
    #pragma unroll
    for (int ti = 0; ti < 8; ++ti)
        #pragma unroll
        for (int nb = 0; nb < 2; ++nb)
            #pragma unroll
            for (int z = 0; z < 4; ++z) acc[ti][nb][z] = 0.f;

    s16x8 af0[8], af1[8];
    float ya0[8], yb0[8], ya1[8], yb1[8];

    #define AFLD(AF, s) do { int c0 = 32 * (s) + cbase; \
        _Pragma("unroll") \
        for (int ti = 0; ti < 8; ++ti) \
            AF[ti] = *(const s16x8*)&M[(size_t)(wr * 128 + ti * 16 + l15) * Cc + c0]; \
        } while (0)

    #define LDY(YA, YB, s) do { int c0 = 32 * (s) + cbase; \
        _Pragma("unroll") \
        for (int j = 0; j < 8; ++j) { \
            YA[j] = Y[(size_t)(c0 + j) * Nn + n0]; \
            YB[j] = Y[(size_t)(c0 + j) * Nn + n0 + 16]; \
        } } while (0)

    #define OSTEP(AF, AFN, YA, YB, s) do { \
        s16x8 bf0, bf1; \
        _Pragma("unroll") \
        for (int j = 0; j < 8; ++j) { bf0[j] = (short)bfh(YA[j]); bf1[j] = (short)bfh(YB[j]); } \
        if ((s) + 1 < 8) AFLD(AFN, (s) + 1); \
        if ((s) + 2 < 8) LDY(YA, YB, (s) + 2); \
        _Pragma("unroll") \
        for (int ti = 0; ti < 8; ++ti) { \
            acc[ti][0] = __builtin_amdgcn_mfma_f32_16x16x32_bf16(AF[ti], bf0, acc[ti][0], 0, 0, 0); \
            acc[ti][1] = __builtin_amdgcn_mfma_f32_16x16x32_bf16(AF[ti], bf1, acc[ti][1], 0, 0, 0); \
        } } while (0)

    AFLD(af0, 0);
    LDY(ya0, yb0, 0);
    LDY(ya1, yb1, 1);
    for (int s = 0; s < 8; s += 2) {
        OSTEP(af0, af1, ya0, yb0, s);
        OSTEP(af1, af0, ya1, yb1, s + 1);
    }
    #undef OSTEP
    #undef LDY
    #undef AFLD

    #pragma unroll
    for (int ti = 0; ti < 8; ++ti)
        #pragma unroll
        for (int nb = 0; nb < 2; ++nb)
            #pragma unroll
            for (int reg = 0; reg < 4; ++reg) {
                int i = wr * 128 + ti * 16 + (lane >> 4) * 4 + reg;
                out[((size_t)b * Cc + i) * Nn + nbase + nb * 16 + l15] =
                    acc[ti][nb][reg] + cb[b * Cc + i];
            }
}

extern "C" void kernel_launch(void* const* d_in, const int* in_sizes, int n_in,
                              void* d_out, int out_size, void* d_ws, size_t ws_size,
                              hipStream_t stream) {
    const float* x  = (const float*)d_in[0];
    const float* y  = (const float*)d_in[1];
    const float* Wq = (const float*)d_in[2];
    const float* bq = (const float*)d_in[3];
    const float* Wk = (const float*)d_in[4];
    const float* bk = (const float*)d_in[5];
    const float* Wv = (const float*)d_in[6];
    const float* bv = (const float*)d_in[7];
    float* out = (float*)d_out;

    float* ws = (float*)d_ws;
    size_t off = 0;
    float* S  = ws + off; off += (size_t)Bb * Cc * Cc;
    float* sx = ws + off; off += Bb * Cc;
    float* sy = ws + off; off += Bb * Cc;
    short* Mbf = (short*)(ws + off); off += (size_t)Bb * Cc * Cc / 2;
    float* cb = ws + off; off += Bb * Cc;
    float* sxp = ws + off; off += (size_t)Bb * 64 * 256;
    float* syp = ws + off; off += (size_t)Bb * 64 * 256;
    float* part = ws + off;

    size_t avail = ws_size / 4 - off;
    int split = 32;
    while (split > 16 && (size_t)split * Bb * Cc * Cc > avail) split >>= 1;

    (void)hipFuncSetAttribute(reinterpret_cast<const void*>(k_gram),
                              hipFuncAttributeMaxDynamicSharedMemorySize, 98304);

    k_gram<<<Bb * split * 2, 512, 98304, stream>>>(x, y, part, sxp, syp, split);
    k_reduceS<<<264, 256, 0, stream>>>(part, sxp, syp, S, sx, sy, split);
    k_attn<<<Bb * 32, 256, 0, stream>>>(S, sx, sy, Wq, Wk, Wv, bq, bk, bv, Mbf, cb);
    k_out_mfma<<<1024, 512, 0, stream>>>(Mbf, y, cb, out);
}

// Round 21
// 218.055 us; speedup vs baseline: 2.5320x; 1.0105x over previous
//
#include <hip/hip_runtime.h>

#define Bb 4
#define Cc 256
#define Nn 32768

typedef short s16x8 __attribute__((ext_vector_type(8)));
typedef float f32x4 __attribute__((ext_vector_type(4)));
typedef float f32x4v __attribute__((ext_vector_type(4)));

__device__ __forceinline__ unsigned short bfh(float f) {
    union { float f; unsigned u; } c; c.f = f;
    unsigned u = c.u + 0x7fffu + ((c.u >> 16) & 1u);
    return (unsigned short)(u >> 16);
}
__device__ __forceinline__ unsigned fbits(float f) {
    union { float f; unsigned u; } c; c.f = f; return c.u;
}
__device__ __forceinline__ float fof(unsigned u) {
    union { unsigned u; float f; } c; c.u = u; return c.f;
}
__device__ __forceinline__ int swz(int l) { return l ^ ((l >> 3) & 6); }

#define GLOAD16(g, l) __builtin_amdgcn_global_load_lds( \
    (const __attribute__((address_space(1))) void*)(g), \
    (__attribute__((address_space(3))) void*)(l), 16, 0, 0)

// hi = trunc-bf16 (top 16 bits), lo = rtn-bf16 of residual. 8 floats -> 2x uint4.
__device__ __forceinline__ void cvt8(f32x4v A, f32x4v B, uint4& h, uint4& l) {
    unsigned a0 = fbits(A.x), a1 = fbits(A.y), a2 = fbits(A.z), a3 = fbits(A.w);
    unsigned b0 = fbits(B.x), b1 = fbits(B.y), b2 = fbits(B.z), b3 = fbits(B.w);
    h.x = __builtin_amdgcn_perm(a1, a0, 0x07060302u);
    h.y = __builtin_amdgcn_perm(a3, a2, 0x07060302u);
    h.z = __builtin_amdgcn_perm(b1, b0, 0x07060302u);
    h.w = __builtin_amdgcn_perm(b3, b2, 0x07060302u);
    unsigned l0 = fbits(A.x - fof(a0 & 0xffff0000u)) + 0x8000u;
    unsigned l1 = fbits(A.y - fof(a1 & 0xffff0000u)) + 0x8000u;
    unsigned l2 = fbits(A.z - fof(a2 & 0xffff0000u)) + 0x8000u;
    unsigned l3 = fbits(A.w - fof(a3 & 0xffff0000u)) + 0x8000u;
    unsigned m0 = fbits(B.x - fof(b0 & 0xffff0000u)) + 0x8000u;
    unsigned m1 = fbits(B.y - fof(b1 & 0xffff0000u)) + 0x8000u;
    unsigned m2 = fbits(B.z - fof(b2 & 0xffff0000u)) + 0x8000u;
    unsigned m3 = fbits(B.w - fof(b3 & 0xffff0000u)) + 0x8000u;
    l.x = __builtin_amdgcn_perm(l1, l0, 0x07060302u);
    l.y = __builtin_amdgcn_perm(l3, l2, 0x07060302u);
    l.z = __builtin_amdgcn_perm(m1, m0, 0x07060302u);
    l.w = __builtin_amdgcn_perm(m3, m2, 0x07060302u);
}
__device__ __forceinline__ float s4(f32x4v v) { return (v.x + v.y) + (v.z + v.w); }

// ---------------- Gram via bf16x3 MFMA, 1-barrier/step LDS double-buffer -----
// x loads NONTEMPORAL (x read exactly once pipeline-wide): keeps y cached for
// sibling blocks and k_out. Measured best: gram ~104-107us (rounds 15/16/17).
__global__ __launch_bounds__(512, 2) void k_gram(const float* __restrict__ x,
                                                 const float* __restrict__ y,
                                                 float* __restrict__ part,
                                                 float* __restrict__ sxp,
                                                 float* __restrict__ syp,
                                                 int nsplit) {
    extern __shared__ short smem[];             // 2 x 24576 shorts

    int G = Bb * nsplit * 2;                    // 256 when split=32
    int chunk = G >> 3;
    int lid = blockIdx.x;
    int bid = (lid & 7) * chunk + (lid >> 3);   // bijective: sibling halves same XCD

    int half = bid & 1;
    int ks = (bid >> 1) % nsplit;
    int b = bid / (2 * nsplit);
    int Kblk = Nn / nsplit;
    int nstep = Kblk >> 5;                      // 32 for split=32 (even)

    const float* X = x + (size_t)b * Cc * Nn + (size_t)(half * 128) * Nn + (size_t)ks * Kblk;
    const float* Y = y + (size_t)b * Cc * Nn + (size_t)ks * Kblk;

    int tid = threadIdx.x;
    int lane = tid & 63;
    int wave = tid >> 6;
    int wr = wave >> 2, wc = wave & 3;          // 2x4 wave grid, 64x64 each

    int xr = tid >> 2, xq = tid & 3;            // X: row, 8-col chunk
    const float* px = X + (size_t)xr * Nn + xq * 8;
    int xl = (xr & 15) + 16 * xq;
    int xo = ((xr >> 4) * 64 + swz(xl)) * 8;    // into XH region (offset 0)
    int yr = tid >> 1, yh2 = tid & 1;           // Y: row, 16-col half
    const float* py = Y + (size_t)yr * Nn + yh2 * 16;
    int yl0 = (yr & 15) + 32 * yh2, yl1 = yl0 + 16;
    int yo0 = ((yr >> 4) * 64 + swz(yl0)) * 8;  // into YH region (offset 8192)
    int yo1 = ((yr >> 4) * 64 + swz(yl1)) * 8;

    f32x4 acc[4][4];
    #pragma unroll
    for (int i = 0; i < 4; ++i)
        #pragma unroll
        for (int j = 0; j < 4; ++j)
            #pragma unroll
            for (int z = 0; z < 4; ++z) acc[i][j][z] = 0.f;

    float xsum = 0.f, ysum = 0.f;
    f32x4v A0[2], B0[4], A1[2], B1[4];

    #define LDX(A, B, kb) do { \
        A[0] = __builtin_nontemporal_load((const f32x4v*)(px + (kb)) + 0); \
        A[1] = __builtin_nontemporal_load((const f32x4v*)(px + (kb)) + 1); \
        B[0] = ((const f32x4v*)(py + (kb)))[0]; B[1] = ((const f32x4v*)(py + (kb)))[1]; \
        B[2] = ((const f32x4v*)(py + (kb)))[2]; B[3] = ((const f32x4v*)(py + (kb)))[3]; \
    } while (0)

    #define COMPUTE(Sb) do { \
        int sl = swz(lane); \
        s16x8 ah[4], al[4]; \
        _Pragma("unroll") \
        for (int i = 0; i < 4; ++i) { \
            int fr = (wr * 4 + i) * 64 + sl; \
            ah[i] = *(const s16x8*)&(Sb)[fr * 8]; \
            al[i] = *(const s16x8*)&(Sb)[4096 + fr * 8]; \
        } \
        _Pragma("unroll") \
        for (int j = 0; j < 4; ++j) { \
            int fr = (wc * 4 + j) * 64 + sl; \
            s16x8 bh = *(const s16x8*)&(Sb)[8192 + fr * 8]; \
            s16x8 bl = *(const s16x8*)&(Sb)[16384 + fr * 8]; \
            _Pragma("unroll") \
            for (int i = 0; i < 4; ++i) { \
                acc[i][j] = __builtin_amdgcn_mfma_f32_16x16x32_bf16(ah[i], bh, acc[i][j], 0, 0, 0); \
                acc[i][j] = __builtin_amdgcn_mfma_f32_16x16x32_bf16(ah[i], bl, acc[i][j], 0, 0, 0); \
                acc[i][j] = __builtin_amdgcn_mfma_f32_16x16x32_bf16(al[i], bh, acc[i][j], 0, 0, 0); \
            } \
        } \
    } while (0)

    // one raw barrier per step: lgkm-only wait (ds_writes visible), no vmcnt drain
    #define GSTEP(A, B, nkb, donext, cur) do { \
        uint4 hx, qxv, hy0, qy0, hy1, qy1; \
        cvt8(A[0], A[1], hx, qxv); \
        cvt8(B[0], B[1], hy0, qy0); \
        cvt8(B[2], B[3], hy1, qy1); \
        xsum += s4(A[0]) + s4(A[1]); \
        if (half == 0) ysum += s4(B[0]) + s4(B[1]) + s4(B[2]) + s4(B[3]); \
        short* Sb = smem + (cur); \
        *(uint4*)&Sb[xo] = hx;  *(uint4*)&Sb[4096 + xo] = qxv; \
        *(uint4*)&Sb[8192 + yo0] = hy0; *(uint4*)&Sb[16384 + yo0] = qy0; \
        *(uint4*)&Sb[8192 + yo1] = hy1; *(uint4*)&Sb[16384 + yo1] = qy1; \
        if (donext) LDX(A, B, nkb); \
        asm volatile("s_waitcnt lgkmcnt(0)" ::: "memory"); \
        __builtin_amdgcn_sched_barrier(0); \
        __builtin_amdgcn_s_barrier(); \
        __builtin_amdgcn_sched_barrier(0); \
        COMPUTE(Sb); \
    } while (0)

    LDX(A0, B0, 0);
    LDX(A1, B1, 32);
    for (int t = 0; t < nstep; t += 2) {
        GSTEP(A0, B0, (t + 2) * 32, t + 2 < nstep, 0);
        GSTEP(A1, B1, (t + 3) * 32, t + 3 < nstep, 24576);
    }
    #undef GSTEP
    #undef COMPUTE
    #undef LDX

    // row-sum partials: X shared by 4 threads (xq), Y by 2 (yh2)
    xsum += __shfl_xor(xsum, 1);
    xsum += __shfl_xor(xsum, 2);
    ysum += __shfl_xor(ysum, 1);
    if (xq == 0) sxp[((size_t)b * nsplit + ks) * 256 + half * 128 + xr] = xsum;
    if (half == 0 && yh2 == 0) syp[((size_t)b * nsplit + ks) * 256 + yr] = ysum;

    // write partials (C/D: col = lane&15, row = (lane>>4)*4 + reg)
    float* P = part + ((size_t)b * nsplit + ks) * Cc * Cc;
    #pragma unroll
    for (int i = 0; i < 4; ++i)
        #pragma unroll
        for (int j = 0; j < 4; ++j)
            #pragma unroll
            for (int reg = 0; reg < 4; ++reg) {
                int gi = half * 128 + wr * 64 + i * 16 + (lane >> 4) * 4 + reg;
                int gj = wc * 64 + j * 16 + (lane & 15);
                P[(size_t)gi * Cc + gj] = acc[i][j][reg];
            }
}

// reduce S partials (float4, nontemporal reads: partials are consumed once);
// blocks >=256 reduce row-sum partials into sx/sy
__global__ __launch_bounds__(256) void k_reduceS(const float* __restrict__ part,
                                                 const float* __restrict__ sxp,
                                                 const float* __restrict__ syp,
                                                 float* __restrict__ S,
                                                 float* __restrict__ sx,
                                                 float* __restrict__ sy, int split) {
    if (blockIdx.x < 256) {
        int t = blockIdx.x * 256 + threadIdx.x;   // 0..65535 float4 units
        int b = t >> 14;
        int rc = t & 16383;
        f32x4v s = {0.f, 0.f, 0.f, 0.f};
        for (int ks = 0; ks < split; ++ks) {
            f32x4v v = __builtin_nontemporal_load(
                (const f32x4v*)(part + (((size_t)b * split + ks) << 16)) + rc);
            s += v;
        }
        ((f32x4v*)S)[t] = s;
    } else {
        int flat = (blockIdx.x - 256) * 256 + threadIdx.x;  // 0..2047
        int b = flat >> 9, rem = flat & 511, which = rem >> 8, c = rem & 255;
        const float* src = (which ? syp : sxp) + (size_t)b * split * 256 + c;
        float s = 0.f;
        for (int ks = 0; ks < split; ++ks)
            s += __builtin_nontemporal_load(src + (size_t)ks * 256);
        (which ? sy : sx)[b * 256 + c] = s;
    }
}

// ---------------- fused scores+softmax+M: 8 rows per block -------------------
__global__ __launch_bounds__(256) void k_attn(const float* __restrict__ S,
                                              const float* __restrict__ sx,
                                              const float* __restrict__ sy,
                                              const float* __restrict__ Wq,
                                              const float* __restrict__ Wk,
                                              const float* __restrict__ Wv,
                                              const float* __restrict__ bq,
                                              const float* __restrict__ bk,
                                              const float* __restrict__ bv,
                                              short* __restrict__ Mbf,
                                              float* __restrict__ cb) {
    __shared__ float wq_lds[8][256];
    __shared__ float u_lds[8][256];
    __shared__ float p_lds[8][256];
    __shared__ float wv_lds[32][256];
    __shared__ float sx_lds[256], sy_lds[256];
    __shared__ float qx_lds[8];

    int b = blockIdx.x >> 5;
    int i0 = (blockIdx.x & 31) << 3;
    int tid = threadIdx.x;
    int lane = tid & 63, wv4 = tid >> 6;

    float bqv[8];
    #pragma unroll
    for (int ii = 0; ii < 8; ++ii) {
        wq_lds[ii][tid] = Wq[(size_t)(i0 + ii) * Cc + tid];
        bqv[ii] = bq[i0 + ii];
    }
    sx_lds[tid] = sx[b * Cc + tid];
    sy_lds[tid] = sy[b * Cc + tid];
    __syncthreads();

    float u[8] = {};
    const float* Sb = S + (size_t)b * Cc * Cc + tid;
    #pragma unroll 4
    for (int c = 0; c < Cc; ++c) {
        float s = Sb[(size_t)c * Cc];
        #pragma unroll
        for (int ii = 0; ii < 8; ++ii) u[ii] += wq_lds[ii][c] * s;
    }
    #pragma unroll
    for (int ii = 0; ii < 8; ++ii) u_lds[ii][tid] = u[ii] + bqv[ii] * sy_lds[tid];

    #pragma unroll
    for (int rr = 0; rr < 2; ++rr) {
        int ii = wv4 * 2 + rr;
        float p = 0.f;
        #pragma unroll
        for (int k = 0; k < 4; ++k) { int c = lane + 64 * k; p += wq_lds[ii][c] * sx_lds[c]; }
        #pragma unroll
        for (int m = 1; m < 64; m <<= 1) p += __shfl_xor(p, m);
        if (lane == 0) qx_lds[ii] = p;
    }
    __syncthreads();

    float sc[8] = {};
    const float* WkRow = Wk + (size_t)tid * Cc;
    for (int ch = 0; ch < 8; ++ch) {
        float wkr[32];
        #pragma unroll
        for (int k = 0; k < 8; ++k)
            *(float4*)&wkr[4 * k] = ((const float4*)(WkRow + ch * 32))[k];
        #pragma unroll
        for (int dd = 0; dd < 32; ++dd) {
            float w = wkr[dd];
            #pragma unroll
            for (int ii = 0; ii < 8; ++ii) sc[ii] += u_lds[ii][ch * 32 + dd] * w;
        }
    }
    float bkj = bk[tid];
    #pragma unroll
    for (int ii = 0; ii < 8; ++ii) {
        sc[ii] += (qx_lds[ii] + 32768.0f * bqv[ii]) * bkj;
        p_lds[ii][tid] = sc[ii];
    }
    __syncthreads();

    #pragma unroll
    for (int rr = 0; rr < 2; ++rr) {
        int ii = wv4 * 2 + rr;
        float v0 = p_lds[ii][lane], v1 = p_lds[ii][lane + 64];
        float v2 = p_lds[ii][lane + 128], v3 = p_lds[ii][lane + 192];
        float mx = fmaxf(fmaxf(v0, v1), fmaxf(v2, v3));
        #pragma unroll
        for (int m = 1; m < 64; m <<= 1) mx = fmaxf(mx, __shfl_xor(mx, m));
        float e0 = expf(v0 - mx), e1 = expf(v1 - mx), e2 = expf(v2 - mx), e3 = expf(v3 - mx);
        float ssum = (e0 + e1) + (e2 + e3);
        #pragma unroll
        for (int m = 1; m < 64; m <<= 1) ssum += __shfl_xor(ssum, m);
        float inv = 1.0f / ssum;
        float w0 = e0 * inv, w1 = e1 * inv, w2 = e2 * inv, w3 = e3 * inv;
        p_lds[ii][lane] = w0; p_lds[ii][lane + 64] = w1;
        p_lds[ii][lane + 128] = w2; p_lds[ii][lane + 192] = w3;
        float cbp = w0 * bv[lane] + w1 * bv[lane + 64] + w2 * bv[lane + 128] + w3 * bv[lane + 192];
        #pragma unroll
        for (int m = 1; m < 64; m <<= 1) cbp += __shfl_xor(cbp, m);
        if (lane == 0) cb[b * Cc + i0 + ii] = cbp;
    }
    __syncthreads();

    float m[8] = {};
    for (int jc = 0; jc < 8; ++jc) {
        #pragma unroll
        for (int k = 0; k < 8; ++k) {
            int fidx = k * 256 + tid;
            int jj = fidx >> 6, f4 = fidx & 63;
            *(float4*)&wv_lds[jj][4 * f4] =
                *(const float4*)(Wv + (size_t)(jc * 32 + jj) * Cc + 4 * f4);
        }
        __syncthreads();
        #pragma unroll 4
        for (int jj = 0; jj < 32; ++jj) {
            float w = wv_lds[jj][tid];
            #pragma unroll
            for (int ii = 0; ii < 8; ++ii) m[ii] += p_lds[ii][jc * 32 + jj] * w;
        }
        __syncthreads();
    }
    #pragma unroll
    for (int ii = 0; ii < 8; ++ii)
        Mbf[((size_t)(b * Cc + i0 + ii)) * Cc + tid] = (short)bfh(m[ii]);
}

// out[b,i,n] = sum_c M[b,i,c]*y[b,c,n] + cb[b,i]
// 512 thr / 8 waves, BARRIER-FREE wave-private LDS y-staging:
// per wave, per step s: y tile c in [32s,32s+32), n in [nbase,nbase+32) is
// DMA'd via 4x global_load_lds (16B/lane coalesced, XOR-swizzled SOURCE so
// ds_read fragments are 2-way-bank = free), double-buffered per wave.
// Counted s_waitcnt vmcnt(8) before ds_reads; no barrier, waves self-overlap.
// FIX vs round 20: af0 reload is for step s+2 (was erroneously s+3 -> af/ybuf
// step mismatch -> absmax 5.1).
__global__ __launch_bounds__(512, 2) void k_out_mfma(const short* __restrict__ Mbf,
                                                     const float* __restrict__ y,
                                                     const float* __restrict__ cb,
                                                     float* __restrict__ out) {
    __shared__ float ylds[16384];   // 8 waves x 2 bufs x 1024 floats (4KB tiles)

    int tid = threadIdx.x;
    int lane = tid & 63;
    int wave = tid >> 6;
    int wr = wave >> 2, wc = wave & 3;
    int bid = blockIdx.x;           // 0..1023
    int b = bid >> 8, grp = bid & 255;
    int nbase = grp * 128 + wc * 32;
    const float* Y = y + (size_t)b * Cc * Nn;
    const short* M = Mbf + (size_t)b * Cc * Cc;
    int l15 = lane & 15, lh = lane >> 4;
    int cbase = 8 * lh;
    int wbase = wave * 2048;

    // staging sources: instr k covers units u=k*64+lane; row c=u>>3 (0..31),
    // chunk-pos u&7 holds global n-chunk (u&7)^key, key=(c>>3)<<1
    const float* ysrc[4];
    #pragma unroll
    for (int k = 0; k < 4; ++k) {
        int u = k * 64 + lane;
        int c = u >> 3;
        int key = (c >> 3) << 1;
        ysrc[k] = Y + (size_t)c * Nn + nbase + (((u & 7) ^ key) << 2);
    }

    f32x4 acc[8][2];
    #pragma unroll
    for (int ti = 0; ti < 8; ++ti)
        #pragma unroll
        for (int nb = 0; nb < 2; ++nb)
            #pragma unroll
            for (int z = 0; z < 4; ++z) acc[ti][nb][z] = 0.f;

    s16x8 af0[8], af1[8];

    #define STAGE(buf, s) do { \
        _Pragma("unroll") \
        for (int k = 0; k < 4; ++k) \
            GLOAD16(ysrc[k] + (size_t)(32 * (s)) * Nn, \
                    &ylds[wbase + (buf) * 1024 + k * 256]); \
        } while (0)

    #define AFLD(AF, s) do { int c0 = 32 * (s) + cbase; \
        _Pragma("unroll") \
        for (int ti = 0; ti < 8; ++ti) \
            AF[ti] = *(const s16x8*)&M[(size_t)(wr * 128 + ti * 16 + l15) * Cc + c0]; \
        } while (0)

    // read key: chunk = (n>>2) ^ (lh<<1); n = l15 (+16 for hi half)
    #define OSTEP(AF, buf) do { \
        asm volatile("s_waitcnt vmcnt(8)" ::: "memory"); \
        __builtin_amdgcn_sched_barrier(0); \
        int rb = wbase + (buf) * 1024; \
        int rkey = lh << 1; \
        s16x8 bf0, bf1; \
        _Pragma("unroll") \
        for (int j = 0; j < 8; ++j) { \
            float f0 = ylds[rb + (cbase + j) * 32 + (((l15 >> 2) ^ rkey) << 2) + (l15 & 3)]; \
            float f1 = ylds[rb + (cbase + j) * 32 + ((((l15 >> 2) + 4) ^ rkey) << 2) + (l15 & 3)]; \
            bf0[j] = (short)bfh(f0); \
            bf1[j] = (short)bfh(f1); \
        } \
        _Pragma("unroll") \
        for (int ti = 0; ti < 8; ++ti) { \
            acc[ti][0] = __builtin_amdgcn_mfma_f32_16x16x32_bf16(AF[ti], bf0, acc[ti][0], 0, 0, 0); \
            acc[ti][1] = __builtin_amdgcn_mfma_f32_16x16x32_bf16(AF[ti], bf1, acc[ti][1], 0, 0, 0); \
        } } while (0)

    STAGE(0, 0);
    STAGE(1, 1);
    AFLD(af0, 0);
    for (int s = 0; s < 8; s += 2) {
        OSTEP(af0, 0);
        if (s + 1 < 8) AFLD(af1, s + 1);
        if (s + 2 < 8) STAGE(0, s + 2);
        OSTEP(af1, 1);
        if (s + 2 < 8) AFLD(af0, s + 2);
        if (s + 3 < 8) STAGE(1, s + 3);
    }
    #undef OSTEP
    #undef AFLD
    #undef STAGE

    #pragma unroll
    for (int ti = 0; ti < 8; ++ti)
        #pragma unroll
        for (int nb = 0; nb < 2; ++nb)
            #pragma unroll
            for (int reg = 0; reg < 4; ++reg) {
                int i = wr * 128 + ti * 16 + (lane >> 4) * 4 + reg;
                out[((size_t)b * Cc + i) * Nn + nbase + nb * 16 + l15] =
                    acc[ti][nb][reg] + cb[b * Cc + i];
            }
}

extern "C" void kernel_launch(void* const* d_in, const int* in_sizes, int n_in,
                              void* d_out, int out_size, void* d_ws, size_t ws_size,
                              hipStream_t stream) {
    const float* x  = (const float*)d_in[0];
    const float* y  = (const float*)d_in[1];
    const float* Wq = (const float*)d_in[2];
    const float* bq = (const float*)d_in[3];
    const float* Wk = (const float*)d_in[4];
    const float* bk = (const float*)d_in[5];
    const float* Wv = (const float*)d_in[6];
    const float* bv = (const float*)d_in[7];
    float* out = (float*)d_out;

    float* ws = (float*)d_ws;
    size_t off = 0;
    float* S  = ws + off; off += (size_t)Bb * Cc * Cc;
    float* sx = ws + off; off += Bb * Cc;
    float* sy = ws + off; off += Bb * Cc;
    short* Mbf = (short*)(ws + off); off += (size_t)Bb * Cc * Cc / 2;
    float* cb = ws + off; off += Bb * Cc;
    float* sxp = ws + off; off += (size_t)Bb * 64 * 256;
    float* syp = ws + off; off += (size_t)Bb * 64 * 256;
    float* part = ws + off;

    size_t avail = ws_size / 4 - off;
    int split = 32;
    while (split > 16 && (size_t)split * Bb * Cc * Cc > avail) split >>= 1;

    (void)hipFuncSetAttribute(reinterpret_cast<const void*>(k_gram),
                              hipFuncAttributeMaxDynamicSharedMemorySize, 98304);

    k_gram<<<Bb * split * 2, 512, 98304, stream>>>(x, y, part, sxp, syp, split);
    k_reduceS<<<264, 256, 0, stream>>>(part, sxp, syp, S, sx, sy, split);
    k_attn<<<Bb * 32, 256, 0, stream>>>(S, sx, sy, Wq, Wk, Wv, bq, bk, bv, Mbf, cb);
    k_out_mfma<<<1024, 512, 0, stream>>>(Mbf, y, cb, out);
}